// Round 8
// baseline (1358.914 us; speedup 1.0000x reference)
//
#include <hip/hip_runtime.h>
#include <hip/hip_fp16.h>
#include <math.h>

#define SELU_SCALE 1.0507009873554805f
#define SELU_ALPHA 1.6732632423543772f

static inline int cdiv(long long a, int b) { return (int)((a + b - 1) / b); }

// packed fp16 max (v_pk_max_f16) — __hmax2 intrinsic is missing on this ROCm
__device__ __forceinline__ __half2 hmax2(__half2 a, __half2 b) {
    __half2 r;
    asm("v_pk_max_f16 %0, %1, %2" : "=v"(r) : "v"(a), "v"(b));
    return r;
}

// ===================== edge preprocessing =====================

__global__ void zero_int_kernel(int* __restrict__ p, int n) {
    int i = blockIdx.x * blockDim.x + threadIdx.x;
    if (i < n) p[i] = 0;
}

__global__ void hist4_kernel(const int* __restrict__ dst, int* __restrict__ cnt, int E) {
    int i = blockIdx.x * blockDim.x + threadIdx.x;
    int base = i * 4;
    if (base + 3 < E) {
        int4 d = *reinterpret_cast<const int4*>(dst + base);
        atomicAdd(&cnt[d.x], 1);
        atomicAdd(&cnt[d.y], 1);
        atomicAdd(&cnt[d.z], 1);
        atomicAdd(&cnt[d.w], 1);
    } else {
        for (int e = base; e < E; ++e) atomicAdd(&cnt[dst[e]], 1);
    }
}

__global__ void dinv_kernel(const int* __restrict__ cnt, float* __restrict__ dinv, int N) {
    int i = blockIdx.x * blockDim.x + threadIdx.x;
    if (i < N) dinv[i] = rsqrtf((float)cnt[i] + 1.0f);  // +1 self loop
}

__global__ void scan_partial_kernel(const int* __restrict__ cnt, int* __restrict__ bsum, int N) {
    __shared__ int sh[256];
    int base = blockIdx.x * 1024;
    int t = threadIdx.x;
    int s = 0;
#pragma unroll
    for (int k = 0; k < 4; ++k) {
        int i = base + t * 4 + k;
        if (i < N) s += cnt[i];
    }
    sh[t] = s;
    __syncthreads();
    for (int o = 128; o > 0; o >>= 1) {
        if (t < o) sh[t] += sh[t + o];
        __syncthreads();
    }
    if (t == 0) bsum[blockIdx.x] = sh[0];
}

__global__ void scan_bsum_par_kernel(int* __restrict__ bsum, int nb) {
    __shared__ int sh[1024];
    int t = threadIdx.x;
    int v = (t < nb) ? bsum[t] : 0;
    sh[t] = v;
    __syncthreads();
    for (int o = 1; o < 1024; o <<= 1) {
        int y = (t >= o) ? sh[t - o] : 0;
        __syncthreads();
        sh[t] += y;
        __syncthreads();
    }
    if (t < nb) bsum[t] = sh[t] - v;
}

__global__ void scan_bsum_serial_kernel(int* __restrict__ bsum, int nb) {
    if (blockIdx.x == 0 && threadIdx.x == 0) {
        int acc = 0;
        for (int i = 0; i < nb; ++i) { int v = bsum[i]; bsum[i] = acc; acc += v; }
    }
}

__global__ void scan_final_kernel(const int* __restrict__ cnt, const int* __restrict__ bsum,
                                  int* __restrict__ row_ptr, int N, int E) {
    __shared__ int sh[256];
    int base = blockIdx.x * 1024;
    int t = threadIdx.x;
    int i0 = base + t * 4;
    int v0 = (i0 + 0 < N) ? cnt[i0 + 0] : 0;
    int v1 = (i0 + 1 < N) ? cnt[i0 + 1] : 0;
    int v2 = (i0 + 2 < N) ? cnt[i0 + 2] : 0;
    int v3 = (i0 + 3 < N) ? cnt[i0 + 3] : 0;
    sh[t] = v0 + v1 + v2 + v3;
    __syncthreads();
    for (int o = 1; o < 256; o <<= 1) {
        int y = (t >= o) ? sh[t - o] : 0;
        __syncthreads();
        sh[t] += y;
        __syncthreads();
    }
    int off = bsum[blockIdx.x] + ((t > 0) ? sh[t - 1] : 0);
    if (i0 + 0 < N) row_ptr[i0 + 0] = off;  off += v0;
    if (i0 + 1 < N) row_ptr[i0 + 1] = off;  off += v1;
    if (i0 + 2 < N) row_ptr[i0 + 2] = off;  off += v2;
    if (i0 + 3 < N) row_ptr[i0 + 3] = off;
    if (blockIdx.x == 0 && t == 0) row_ptr[N] = E;
}

__global__ void fill_sorted4_kernel(const int* __restrict__ src, const int* __restrict__ dst,
                                    const int* __restrict__ row_ptr, int* __restrict__ cursor,
                                    int* __restrict__ sorted_src, int E) {
    int i = blockIdx.x * blockDim.x + threadIdx.x;
    int base = i * 4;
    if (base + 3 < E) {
        int4 d = *reinterpret_cast<const int4*>(dst + base);
        int4 s = *reinterpret_cast<const int4*>(src + base);
        int r0 = row_ptr[d.x];
        int r1 = row_ptr[d.y];
        int r2 = row_ptr[d.z];
        int r3 = row_ptr[d.w];
        int k0 = atomicAdd(&cursor[d.x], 1);
        int k1 = atomicAdd(&cursor[d.y], 1);
        int k2 = atomicAdd(&cursor[d.z], 1);
        int k3 = atomicAdd(&cursor[d.w], 1);
        sorted_src[r0 + k0] = s.x;
        sorted_src[r1 + k1] = s.y;
        sorted_src[r2 + k2] = s.z;
        sorted_src[r3 + k3] = s.w;
    } else {
        for (int e = base; e < E; ++e) {
            int dd = dst[e];
            int pos = row_ptr[dd] + atomicAdd(&cursor[dd], 1);
            sorted_src[pos] = src[e];
        }
    }
}

// ===================== fp16 row helpers (packed half2) =====================

template <int SH>
__device__ __forceinline__ void load_row_h2(__half2* __restrict__ acc, const __half* __restrict__ row) {
#pragma unroll
    for (int u = 0; u < SH / 8; ++u) {
        union { float4 f4; __half2 h2[4]; } ld;
        ld.f4 = *reinterpret_cast<const float4*>(row + u * 8);
#pragma unroll
        for (int k = 0; k < 4; ++k) acc[u * 4 + k] = ld.h2[k];
    }
}

template <int SH>
__device__ __forceinline__ void fmax_row_h2(__half2* __restrict__ acc, const __half* __restrict__ row) {
#pragma unroll
    for (int u = 0; u < SH / 8; ++u) {
        union { float4 f4; __half2 h2[4]; } ld;
        ld.f4 = *reinterpret_cast<const float4*>(row + u * 8);
#pragma unroll
        for (int k = 0; k < 4; ++k) acc[u * 4 + k] = hmax2(acc[u * 4 + k], ld.h2[k]);
    }
}

// cross-lane max over LPN-lane groups (packed)
template <int SH, int LPN>
__device__ __forceinline__ void combine_max_h2(__half2* __restrict__ acc) {
#pragma unroll
    for (int m = 1; m < LPN; m <<= 1) {
#pragma unroll
        for (int i = 0; i < SH / 2; ++i) {
            int a = *reinterpret_cast<int*>(&acc[i]);
            int v = __shfl_xor(a, m, 64);
            __half2 o = *reinterpret_cast<__half2*>(&v);
            acc[i] = hmax2(acc[i], o);
        }
    }
}

template <int FOUT, int SOUTH>
__device__ __forceinline__ void store_row_h(__half* __restrict__ op,
                                            const float* __restrict__ vals, float dv) {
#pragma unroll
    for (int u = 0; u < SOUTH / 8; ++u) {
        union { float4 f4; __half2 h2[4]; } pk;
#pragma unroll
        for (int k = 0; k < 4; ++k) {
            int f0 = u * 8 + 2 * k, f1 = f0 + 1;
            float a = (f0 < FOUT) ? vals[(f0 < FOUT) ? f0 : 0] * dv : 0.0f;
            float b = (f1 < FOUT) ? vals[(f1 < FOUT) ? f1 : 0] * dv : 0.0f;
            pk.h2[k] = __floats2half2_rn(a, b);
        }
        *reinterpret_cast<float4*>(op + u * 8) = pk.f4;
    }
}

// ===================== layer kernels =====================

// layer-1 GEMM: u1[n,:] = half((x[n,:] @ W1) * dinv[n])
template <int FIN, int FOUT, int SOUTH>
__global__ void gemm_scale_kernel(const float* __restrict__ h,
                                  const float* __restrict__ W,
                                  const float* __restrict__ dinv,
                                  __half* __restrict__ u,
                                  int N) {
    int n = blockIdx.x * blockDim.x + threadIdx.x;
    if (n >= N) return;
    const float* hr = h + (long long)n * FIN;
    float acc[FOUT];
#pragma unroll
    for (int c = 0; c < FOUT; ++c) acc[c] = 0.0f;
#pragma unroll
    for (int fi = 0; fi < FIN; ++fi) {
        float hv = hr[fi];
#pragma unroll
        for (int c = 0; c < FOUT; ++c) acc[c] += hv * W[fi * FOUT + c];
    }
    store_row_h<FOUT, SOUTH>(u + (long long)n * SOUTH, acc, dinv[n]);
}

// fused agg + next-layer GEMM, LPN lanes per node
template <int SPREVH, int FPREV, int FOUT, int SOUTH, int LPN>
__global__ void agg_gemm_kernel(const __half* __restrict__ u,
                                const int* __restrict__ row_ptr,
                                const int* __restrict__ sorted_src,
                                const float* __restrict__ dinv,
                                const float* __restrict__ bprev,
                                const float* __restrict__ W,
                                __half* __restrict__ uout,
                                int N) {
    int gid = blockIdx.x * blockDim.x + threadIdx.x;
    int n = gid / LPN;
    int lane = gid & (LPN - 1);
    if (n >= N) return;
    __half2 acc[SPREVH / 2];
    load_row_h2<SPREVH>(acc, u + (long long)n * SPREVH);  // self loop
    int j0 = row_ptr[n], j1 = row_ptr[n + 1];
    int j = j0 + lane;
    for (; j + LPN < j1; j += 2 * LPN) {
        const __half* r0 = u + (long long)sorted_src[j] * SPREVH;
        const __half* r1 = u + (long long)sorted_src[j + LPN] * SPREVH;
        fmax_row_h2<SPREVH>(acc, r0);
        fmax_row_h2<SPREVH>(acc, r1);
    }
    if (j < j1) fmax_row_h2<SPREVH>(acc, u + (long long)sorted_src[j] * SPREVH);
    combine_max_h2<SPREVH, LPN>(acc);

    float af[SPREVH];
#pragma unroll
    for (int i = 0; i < SPREVH / 2; ++i) {
        float2 p = __half22float2(acc[i]);
        af[2 * i] = p.x;
        af[2 * i + 1] = p.y;
    }
    float dv = dinv[n];
    float h[FPREV];
#pragma unroll
    for (int f = 0; f < FPREV; ++f) {
        float v = dv * af[f] + bprev[f];
        h[f] = (v > 0.0f) ? (SELU_SCALE * v) : (SELU_SCALE * SELU_ALPHA * (expf(v) - 1.0f));
    }
    float outv[FOUT];
#pragma unroll
    for (int c = 0; c < FOUT; ++c) outv[c] = 0.0f;
#pragma unroll
    for (int fi = 0; fi < FPREV; ++fi) {
        float hv = h[fi];
#pragma unroll
        for (int c = 0; c < FOUT; ++c) outv[c] += hv * W[fi * FOUT + c];
    }
    // lane-split 16B-chunk stores
    __half* op = uout + (long long)n * SOUTH;
#pragma unroll
    for (int c8 = 0; c8 < SOUTH / 8; ++c8) {
        if ((c8 & (LPN - 1)) != lane) continue;
        union { float4 f4; __half2 h2[4]; } pk;
#pragma unroll
        for (int k = 0; k < 4; ++k) {
            int f0 = c8 * 8 + 2 * k, f1 = f0 + 1;
            float a = (f0 < FOUT) ? outv[(f0 < FOUT) ? f0 : 0] * dv : 0.0f;
            float b = (f1 < FOUT) ? outv[(f1 < FOUT) ? f1 : 0] * dv : 0.0f;
            pk.h2[k] = __floats2half2_rn(a, b);
        }
        *reinterpret_cast<float4*>(op + c8 * 8) = pk.f4;
    }
}

// final aggregation (layer 4): fp32 output stride F, LPN lanes per node
template <int SH, int F, int LPN>
__global__ void agg_selu_kernel(const __half* __restrict__ u,
                                const int* __restrict__ row_ptr,
                                const int* __restrict__ sorted_src,
                                const float* __restrict__ dinv,
                                const float* __restrict__ b,
                                float* __restrict__ hout,
                                int N) {
    int gid = blockIdx.x * blockDim.x + threadIdx.x;
    int n = gid / LPN;
    int lane = gid & (LPN - 1);
    if (n >= N) return;
    __half2 acc[SH / 2];
    load_row_h2<SH>(acc, u + (long long)n * SH);
    int j0 = row_ptr[n], j1 = row_ptr[n + 1];
    int j = j0 + lane;
    for (; j + LPN < j1; j += 2 * LPN) {
        const __half* r0 = u + (long long)sorted_src[j] * SH;
        const __half* r1 = u + (long long)sorted_src[j + LPN] * SH;
        fmax_row_h2<SH>(acc, r0);
        fmax_row_h2<SH>(acc, r1);
    }
    if (j < j1) fmax_row_h2<SH>(acc, u + (long long)sorted_src[j] * SH);
    combine_max_h2<SH, LPN>(acc);

    float dv = dinv[n];
    float* op = hout + (long long)n * F;
#pragma unroll
    for (int q = 0; q < F / 4; ++q) {
        if ((q & (LPN - 1)) != lane) continue;
        float4 o;
        float* ov = &o.x;
#pragma unroll
        for (int k = 0; k < 4; ++k) {
            int f = 4 * q + k;
            float2 p = __half22float2(acc[f / 2]);
            float raw = (f & 1) ? p.y : p.x;
            float v = dv * raw + b[f];
            ov[k] = (v > 0.0f) ? (SELU_SCALE * v) : (SELU_SCALE * SELU_ALPHA * (expf(v) - 1.0f));
        }
        *reinterpret_cast<float4*>(op + 4 * q) = o;
    }
}

// ===================== pooling =====================

__global__ void segstart_kernel(const int* __restrict__ batch, int* __restrict__ seg, int N, int G) {
    int g = blockIdx.x * blockDim.x + threadIdx.x;
    if (g > G) return;
    if (g == G) { seg[G] = N; return; }
    int lo = 0, hi = N;
    while (lo < hi) { int mid = (lo + hi) >> 1; if (batch[mid] < g) lo = mid + 1; else hi = mid; }
    seg[g] = lo;
}

__global__ void pool_kernel(const float* __restrict__ h,
                            const int* __restrict__ seg,
                            float* __restrict__ pooled,
                            int G) {
    int idx = blockIdx.x * blockDim.x + threadIdx.x;  // G * 9
    if (idx >= G * 9) return;
    int g = idx / 9;
    int t = idx - g * 9;
    int lo = seg[g], hi = seg[g + 1];
    float4 acc = make_float4(0.f, 0.f, 0.f, 0.f);
    for (int n = lo; n < hi; ++n) {
        float4 v = *reinterpret_cast<const float4*>(h + (long long)n * 36 + 4 * t);
        acc.x += v.x; acc.y += v.y; acc.z += v.z; acc.w += v.w;
    }
    *reinterpret_cast<float4*>(pooled + (long long)g * 36 + 4 * t) = acc;
}

// ===================== MLP head =====================

__global__ void mlp1_kernel(const float* __restrict__ pooled,
                            const float* __restrict__ lw1,
                            const float* __restrict__ lb1,
                            float* __restrict__ y1,
                            int G) {
    __shared__ float Ws[36 * 96];
    for (int i = threadIdx.x; i < 36 * 96; i += blockDim.x) Ws[i] = lw1[i];
    __syncthreads();
    int idx = blockIdx.x * blockDim.x + threadIdx.x;
    if (idx >= G * 96) return;
    int g = idx / 96;
    int j = idx - g * 96;
    const float* pr = pooled + (long long)g * 36;
    float acc = lb1[j];
#pragma unroll
    for (int k4 = 0; k4 < 9; ++k4) {
        float4 pv = *reinterpret_cast<const float4*>(pr + 4 * k4);
        acc += pv.x * Ws[(4 * k4 + 0) * 96 + j];
        acc += pv.y * Ws[(4 * k4 + 1) * 96 + j];
        acc += pv.z * Ws[(4 * k4 + 2) * 96 + j];
        acc += pv.w * Ws[(4 * k4 + 3) * 96 + j];
    }
    y1[idx] = fmaxf(acc, 0.0f);
}

__global__ void mlp2_kernel(const float* __restrict__ y1,
                            const float* __restrict__ lw2,
                            const float* __restrict__ lb2,
                            float* __restrict__ out,
                            int G) {
    __shared__ float Ws[96 * 27];
    for (int i = threadIdx.x; i < 96 * 27; i += blockDim.x) Ws[i] = lw2[i];
    __syncthreads();
    int idx = blockIdx.x * blockDim.x + threadIdx.x;
    if (idx >= G * 27) return;
    int g = idx / 27;
    int c = idx - g * 27;
    const float* yr = y1 + (long long)g * 96;
    float acc = lb2[c];
#pragma unroll
    for (int k4 = 0; k4 < 24; ++k4) {
        float4 yv = *reinterpret_cast<const float4*>(yr + 4 * k4);
        acc += yv.x * Ws[(4 * k4 + 0) * 27 + c];
        acc += yv.y * Ws[(4 * k4 + 1) * 27 + c];
        acc += yv.z * Ws[(4 * k4 + 2) * 27 + c];
        acc += yv.w * Ws[(4 * k4 + 3) * 27 + c];
    }
    out[idx] = fmaxf(acc, 0.0f);
}

// ===================== launch =====================

extern "C" void kernel_launch(void* const* d_in, const int* in_sizes, int n_in,
                              void* d_out, int out_size, void* d_ws, size_t ws_size,
                              hipStream_t stream) {
    const float* x     = (const float*)d_in[0];
    const int*   ei    = (const int*)d_in[1];
    const int*   batch = (const int*)d_in[2];
    const float* W1  = (const float*)d_in[4];
    const float* b1  = (const float*)d_in[5];
    const float* W2  = (const float*)d_in[6];
    const float* b2  = (const float*)d_in[7];
    const float* W3  = (const float*)d_in[8];
    const float* b3  = (const float*)d_in[9];
    const float* W4  = (const float*)d_in[10];
    const float* b4  = (const float*)d_in[11];
    const float* lw1 = (const float*)d_in[12];
    const float* lb1 = (const float*)d_in[13];
    const float* lw2 = (const float*)d_in[14];
    const float* lb2 = (const float*)d_in[15];
    float* out = (float*)d_out;

    const int N = in_sizes[0] / 75;
    const int E = in_sizes[1] / 2;
    const int G = out_size / 27;
    const int* srcp = ei;
    const int* dstp = ei + E;

    char* ws = (char*)d_ws;
    size_t off = 0;
    auto carve = [&](size_t bytes) -> char* {
        char* p = ws + off;
        off = (off + bytes + 255) & ~(size_t)255;
        return p;
    };
    int*    cnt        = (int*)carve((size_t)N * 4);
    int*    row_ptr    = (int*)carve((size_t)(N + 1) * 4);
    int*    sorted_src = (int*)carve((size_t)E * 4);
    int*    bsum       = (int*)carve((size_t)cdiv(N, 1024) * 4 + 4);
    int*    seg        = (int*)carve((size_t)(G + 1) * 4);
    float*  dinv       = (float*)carve((size_t)N * 4);
    char*   Abuf       = carve((size_t)N * 36 * 4);
    char*   Bbuf       = carve((size_t)N * 36 * 4);
    float*  pooled     = (float*)carve((size_t)G * 36 * 4);
    float*  y1         = (float*)carve((size_t)G * 96 * 4);
    (void)ws_size; (void)n_in;

    const int BLK = 256;
    const int nb = cdiv(N, 1024);
    const int LPN = 4;

    // ---- edge preprocessing ----
    zero_int_kernel<<<cdiv(N, BLK), BLK, 0, stream>>>(cnt, N);
    hist4_kernel<<<cdiv(cdiv(E, 4), BLK), BLK, 0, stream>>>(dstp, cnt, E);
    dinv_kernel<<<cdiv(N, BLK), BLK, 0, stream>>>(cnt, dinv, N);
    scan_partial_kernel<<<nb, 256, 0, stream>>>(cnt, bsum, N);
    if (nb <= 1024) scan_bsum_par_kernel<<<1, 1024, 0, stream>>>(bsum, nb);
    else            scan_bsum_serial_kernel<<<1, 64, 0, stream>>>(bsum, nb);
    scan_final_kernel<<<nb, 256, 0, stream>>>(cnt, bsum, row_ptr, N, E);
    zero_int_kernel<<<cdiv(N, BLK), BLK, 0, stream>>>(cnt, N);  // cursor = 0
    fill_sorted4_kernel<<<cdiv(cdiv(E, 4), BLK), BLK, 0, stream>>>(srcp, dstp, row_ptr, cnt, sorted_src, E);
    segstart_kernel<<<cdiv(G + 1, BLK), BLK, 0, stream>>>(batch, seg, N, G);

    // fp16 u strides (halves): u1=16 (32B), u2=32 (64B line), u3=32 (64B line), u4=40 (80B)
    __half* u1 = (__half*)Bbuf;
    __half* u2 = (__half*)Abuf;
    __half* u3 = (__half*)Bbuf;
    __half* u4 = (__half*)Abuf;
    float*  h4 = (float*)Bbuf;

    gemm_scale_kernel<75, 15, 16><<<cdiv(N, BLK), BLK, 0, stream>>>(x, W1, dinv, u1, N);
    agg_gemm_kernel<16, 15, 20, 32, LPN><<<cdiv((long long)N * LPN, BLK), BLK, 0, stream>>>(u1, row_ptr, sorted_src, dinv, b1, W2, u2, N);
    agg_gemm_kernel<32, 20, 27, 32, LPN><<<cdiv((long long)N * LPN, BLK), BLK, 0, stream>>>(u2, row_ptr, sorted_src, dinv, b2, W3, u3, N);
    agg_gemm_kernel<32, 27, 36, 40, LPN><<<cdiv((long long)N * LPN, BLK), BLK, 0, stream>>>(u3, row_ptr, sorted_src, dinv, b3, W4, u4, N);
    agg_selu_kernel<40, 36, LPN><<<cdiv((long long)N * LPN, BLK), BLK, 0, stream>>>(u4, row_ptr, sorted_src, dinv, b4, h4, N);

    // ---- pool: segmented sum (batch_vec is sorted) ----
    pool_kernel<<<cdiv((long long)G * 9, BLK), BLK, 0, stream>>>(h4, seg, pooled, G);

    // ---- MLP head ----
    mlp1_kernel<<<cdiv((long long)G * 96, BLK), BLK, 0, stream>>>(pooled, lw1, lb1, y1, G);
    mlp2_kernel<<<cdiv((long long)G * 27, BLK), BLK, 0, stream>>>(y1, lw2, lb2, out, G);
}